// Round 5
// baseline (262.600 us; speedup 1.0000x reference)
//
#include <hip/hip_runtime.h>
#include <math.h>

#define N_ROWS 131072
#define DIM 64
#define K_CODES 1024
#define CHUNK 128          // codes per LDS stage (32 KB hi+lo)
#define BLK_ROWS 128       // rows per workgroup (rg=2 per wave)
#define THREADS 256
#define NBLK (N_ROWS / BLK_ROWS)   // 1024

typedef __attribute__((ext_vector_type(8))) short bf16x8;
typedef __attribute__((ext_vector_type(4))) float f32x4;

__device__ inline unsigned short bf16_rn(float f) {
    unsigned int u = __builtin_bit_cast(unsigned int, f);
    u += 0x7fffu + ((u >> 16) & 1u);   // round-to-nearest-even
    return (unsigned short)(u >> 16);
}
__device__ inline float bf16_to_f(unsigned short h) {
    unsigned int u = ((unsigned int)h) << 16;
    return __builtin_bit_cast(float, u);
}

// ws layout:
//   [0,8)    double loss_sum        [128,132) u32 done
//   [256,4352) u32 counts[1024]     [8192,12288) f32 esq[1024]
//   [16384,+128K) bf16 cbhi = bf16(-2c)   [147456,+128K) bf16 cblo = bf16(-2c - hi)

__global__ void vq_prep(const float* __restrict__ cb, float* __restrict__ esq,
                        uint4* __restrict__ cbhi, uint4* __restrict__ cblo,
                        unsigned int* __restrict__ counts,
                        unsigned long long* __restrict__ loss,
                        unsigned int* __restrict__ done) {
    const int k = blockIdx.x * blockDim.x + threadIdx.x;   // one code per thread
    if (k >= K_CODES) return;
    counts[k] = 0u;
    if (k == 0) { *loss = 0ull; *done = 0u; }
    const float4* c = (const float4*)(cb + (size_t)k * DIM);
    float s = 0.f;
#pragma unroll
    for (int i = 0; i < 8; ++i) {
        float4 a = c[2 * i], b = c[2 * i + 1];
        float f[8] = {a.x, a.y, a.z, a.w, b.x, b.y, b.z, b.w};
        unsigned int hw[4], lw[4];
#pragma unroll
        for (int p = 0; p < 4; ++p) {
            float f0 = f[2 * p], f1 = f[2 * p + 1];
            s = fmaf(f0, f0, s);
            s = fmaf(f1, f1, s);
            float m0 = -2.f * f0, m1 = -2.f * f1;      // exact scaling
            unsigned short h0 = bf16_rn(m0), h1 = bf16_rn(m1);
            unsigned short l0 = bf16_rn(m0 - bf16_to_f(h0));
            unsigned short l1 = bf16_rn(m1 - bf16_to_f(h1));
            hw[p] = (unsigned int)h0 | ((unsigned int)h1 << 16);
            lw[p] = (unsigned int)l0 | ((unsigned int)l1 << 16);
        }
        cbhi[(size_t)k * 8 + i] = make_uint4(hw[0], hw[1], hw[2], hw[3]);
        cblo[(size_t)k * 8 + i] = make_uint4(lw[0], lw[1], lw[2], lw[3]);
    }
    esq[k] = s;
}

// Load A-side (codebook) fragments for sub-tile tb from swizzled LDS.
#define LOADF(H0, H1, L0, L1, EV, tb) do {                              \
    const int _a0 = aoff0 + (tb) * 2048;                                \
    const int _a1 = aoff1 + (tb) * 2048;                                \
    H0 = *(const bf16x8*)(s_ab + _a0);                                  \
    H1 = *(const bf16x8*)(s_ab + _a1);                                  \
    L0 = *(const bf16x8*)(s_ab + 16384 + _a0);                          \
    L1 = *(const bf16x8*)(s_ab + 16384 + _a1);                          \
    EV = *(const float4*)(eb + (tb) * 16);                              \
} while (0)

// 12 MFMAs, term-outer / rg-inner (2 independent chains).
// acc init = esq (codebook pre-scaled by -2 -> acc ends as dist').
#define BURST(H0, H1, L0, L1, EV, ACC) do {                             \
    _Pragma("unroll") for (int rg = 0; rg < 2; ++rg)                    \
        ACC[rg] = (f32x4){EV.x, EV.y, EV.z, EV.w};                      \
    _Pragma("unroll") for (int rg = 0; rg < 2; ++rg)                    \
        ACC[rg] = __builtin_amdgcn_mfma_f32_16x16x32_bf16(H0, xh[rg][0], ACC[rg], 0, 0, 0); \
    _Pragma("unroll") for (int rg = 0; rg < 2; ++rg)                    \
        ACC[rg] = __builtin_amdgcn_mfma_f32_16x16x32_bf16(H1, xh[rg][1], ACC[rg], 0, 0, 0); \
    _Pragma("unroll") for (int rg = 0; rg < 2; ++rg)                    \
        ACC[rg] = __builtin_amdgcn_mfma_f32_16x16x32_bf16(H0, xl[rg][0], ACC[rg], 0, 0, 0); \
    _Pragma("unroll") for (int rg = 0; rg < 2; ++rg)                    \
        ACC[rg] = __builtin_amdgcn_mfma_f32_16x16x32_bf16(H1, xl[rg][1], ACC[rg], 0, 0, 0); \
    _Pragma("unroll") for (int rg = 0; rg < 2; ++rg)                    \
        ACC[rg] = __builtin_amdgcn_mfma_f32_16x16x32_bf16(L0, xh[rg][0], ACC[rg], 0, 0, 0); \
    _Pragma("unroll") for (int rg = 0; rg < 2; ++rg)                    \
        ACC[rg] = __builtin_amdgcn_mfma_f32_16x16x32_bf16(L1, xh[rg][1], ACC[rg], 0, 0, 0); \
} while (0)

// Compare a FINISHED acc (one tb behind -> no MFMA-latency stall).
#define COMPARE(ACC) do {                                               \
    _Pragma("unroll") for (int rg = 0; rg < 2; ++rg) {                  \
        _Pragma("unroll") for (int j = 0; j < 4; ++j) {                 \
            float _tv = ACC[rg][j];                                     \
            if (_tv < best[rg]) { best[rg] = _tv; bidx[rg] = kbase + j; } \
        }                                                               \
    }                                                                   \
} while (0)

__global__ __launch_bounds__(THREADS, 4) void vq_main(
    const float* __restrict__ x, const float* __restrict__ cb,
    const float* __restrict__ esq_g,
    const uint4* __restrict__ cbhi, const uint4* __restrict__ cblo,
    float* __restrict__ outq,
    unsigned long long* __restrict__ loss_sum,
    unsigned int* __restrict__ counts,
    unsigned int* __restrict__ done,
    float* __restrict__ out)
{
    __shared__ __align__(16) char s_ab[CHUNK * 256];   // hi [0,16K) + lo [16K,32K)
    __shared__ __align__(16) float s_esq[K_CODES];     // 4 KB
    __shared__ float s_red[THREADS];
    __shared__ int s_last;

    const int t  = threadIdx.x;
    const int w  = t >> 6;        // wave 0..3
    const int l  = t & 63;        // lane
    const int g  = l >> 4;        // k-group 0..3
    const int li = l & 15;

    const int R0 = blockIdx.x * BLK_ROWS;

    // ---- x rows -> split-bf16 B fragments, registers all kernel ----
    bf16x8 xh[2][2], xl[2][2];
#pragma unroll
    for (int rg = 0; rg < 2; ++rg) {
        const int row = R0 + w * 32 + rg * 16 + li;
        const float* xp = x + (size_t)row * DIM;
#pragma unroll
        for (int h = 0; h < 2; ++h) {
            const float4 p0 = *(const float4*)(xp + h * 32 + g * 8);
            const float4 p1 = *(const float4*)(xp + h * 32 + g * 8 + 4);
            float f[8] = {p0.x, p0.y, p0.z, p0.w, p1.x, p1.y, p1.z, p1.w};
            bf16x8 hv, lv;
#pragma unroll
            for (int j = 0; j < 8; ++j) {
                unsigned short hb = bf16_rn(f[j]);
                unsigned short lb = bf16_rn(f[j] - bf16_to_f(hb));
                hv[j] = (short)hb;
                lv[j] = (short)lb;
            }
            xh[rg][h] = hv;
            xl[rg][h] = lv;
        }
    }

    ((float4*)s_esq)[t] = ((const float4*)esq_g)[t];   // covered by chunk-0 barrier

    float best[2];
    int   bidx[2];
#pragma unroll
    for (int rg = 0; rg < 2; ++rg) { best[rg] = 3.4e38f; bidx[rg] = 0; }

    // per-lane swizzle is tb-invariant: c = tb*16+li -> c&7 == li&7
    const int sw = li & 7;
    const int aoff0 = li * 128 + ((g ^ sw) << 4);        // k-slot g   (k 0..31)
    const int aoff1 = li * 128 + (((4 + g) ^ sw) << 4);  // k-slot 4+g (k 32..63)

    for (int chunk = 0; chunk < K_CODES / CHUNK; ++chunk) {
        if (chunk) __syncthreads();
#pragma unroll 2
        for (int i = 0; i < 4; ++i) {
            const int n = i * THREADS + t;               // 16B-chunk id 0..1023
            const int c = n >> 3, s = n & 7;
            const int dst = c * 128 + ((s ^ (c & 7)) << 4);
            *(uint4*)(s_ab + dst)         = cbhi[(size_t)(chunk * CHUNK + c) * 8 + s];
            *(uint4*)(s_ab + 16384 + dst) = cblo[(size_t)(chunk * CHUNK + c) * 8 + s];
        }
        __syncthreads();

        int kbase = chunk * CHUNK + g * 4;               // compare-time index base
        const float* eb = s_esq + chunk * CHUNK + g * 4;

        bf16x8 Ah0, Ah1, Al0, Al1, Bh0, Bh1, Bl0, Bl1;
        float4 eA, eB;
        f32x4 accA[2], accB[2];

        LOADF(Ah0, Ah1, Al0, Al1, eA, 0);
        LOADF(Bh0, Bh1, Bl0, Bl1, eB, 1);
        BURST(Ah0, Ah1, Al0, Al1, eA, accA);             // tb=0
#pragma unroll 1
        for (int p = 0; p < CHUNK / 32 - 1; ++p) {       // p = 0..2
            LOADF(Ah0, Ah1, Al0, Al1, eA, 2 * p + 2);    // prefetch tb=2p+2
            BURST(Bh0, Bh1, Bl0, Bl1, eB, accB);         // tb=2p+1
            COMPARE(accA); kbase += 16;                  // tb=2p
            LOADF(Bh0, Bh1, Bl0, Bl1, eB, 2 * p + 3);    // prefetch tb=2p+3
            BURST(Ah0, Ah1, Al0, Al1, eA, accA);         // tb=2p+2
            COMPARE(accB); kbase += 16;                  // tb=2p+1
        }
        BURST(Bh0, Bh1, Bl0, Bl1, eB, accB);             // tb=7
        COMPARE(accA); kbase += 16;                      // tb=6
        COMPARE(accB); kbase += 16;                      // tb=7
    }

    // ---- merge argmin across the 4 k-groups ----
#pragma unroll
    for (int rg = 0; rg < 2; ++rg) {
#pragma unroll
        for (int d = 16; d <= 32; d <<= 1) {
            float ob = __shfl_xor(best[rg], d, 64);
            int   oi = __shfl_xor(bidx[rg], d, 64);
            if (ob < best[rg] || (ob == best[rg] && oi < bidx[rg])) {
                best[rg] = ob;
                bidx[rg] = oi;
            }
        }
    }

    // ---- epilogue: gather code, write quantized, loss partial, histogram ----
    float ls = 0.f;
#pragma unroll
    for (int rg = 0; rg < 2; ++rg) {
        const int row = R0 + w * 32 + rg * 16 + li;
        const int idx = bidx[rg];
        if (g == 0) atomicAdd(&counts[idx], 1u);
        const float4* qp = (const float4*)(cb + (size_t)idx * DIM);
        float* op = outq + (size_t)row * DIM;
#pragma unroll
        for (int h = 0; h < 2; ++h) {
            float4 q0 = qp[h * 8 + g * 2];
            float4 q1 = qp[h * 8 + g * 2 + 1];
            *(float4*)(op + h * 32 + g * 8)     = q0;
            *(float4*)(op + h * 32 + g * 8 + 4) = q1;
            float qq[8] = {q0.x, q0.y, q0.z, q0.w, q1.x, q1.y, q1.z, q1.w};
#pragma unroll
            for (int j = 0; j < 8; ++j) {
                float xv = bf16_to_f((unsigned short)xh[rg][h][j])
                         + bf16_to_f((unsigned short)xl[rg][h][j]);
                float e = qq[j] - xv;
                ls = fmaf(e, e, ls);
            }
        }
    }

    s_red[t] = ls;
    __syncthreads();
#pragma unroll
    for (int s = THREADS / 2; s > 0; s >>= 1) {
        if (t < s) s_red[t] += s_red[t + s];
        __syncthreads();
    }
    if (t == 0) atomicAdd((double*)loss_sum, (double)s_red[0]);

    // ---- last block finalizes loss + perplexity ----
    if (t == 0) {
        __threadfence();
        unsigned int prev = __hip_atomic_fetch_add(done, 1u, __ATOMIC_ACQ_REL,
                                                   __HIP_MEMORY_SCOPE_AGENT);
        s_last = (prev == (unsigned int)(NBLK - 1));
    }
    __syncthreads();
    if (s_last) {
        float part = 0.f;
#pragma unroll
        for (int j = 0; j < 4; ++j) {
            unsigned int c = __hip_atomic_load(&counts[t + j * 256], __ATOMIC_RELAXED,
                                               __HIP_MEMORY_SCOPE_AGENT);
            float pr = (float)c * (1.0f / (float)N_ROWS);
            part += pr * logf(pr + 1e-10f);
        }
        s_red[t] = part;
        __syncthreads();
#pragma unroll
        for (int s = THREADS / 2; s > 0; s >>= 1) {
            if (t < s) s_red[t] += s_red[t + s];
            __syncthreads();
        }
        if (t == 0) {
            unsigned long long lb = __hip_atomic_load(loss_sum, __ATOMIC_RELAXED,
                                                      __HIP_MEMORY_SCOPE_AGENT);
            double ls_d = __builtin_bit_cast(double, lb);
            out[0] = (float)(1.25 * ls_d / (double)((size_t)N_ROWS * DIM));
            out[1 + (size_t)N_ROWS * DIM] = expf(-s_red[0]);
        }
    }
}

extern "C" void kernel_launch(void* const* d_in, const int* in_sizes, int n_in,
                              void* d_out, int out_size, void* d_ws, size_t ws_size,
                              hipStream_t stream) {
    const float* x  = (const float*)d_in[0];   // [131072, 64] f32
    const float* cb = (const float*)d_in[1];   // [1024, 64] f32
    float* out = (float*)d_out;                // [1 + N*D + 1] f32
    char* ws = (char*)d_ws;

    unsigned long long* loss   = (unsigned long long*)ws;
    unsigned int*       done   = (unsigned int*)(ws + 128);
    unsigned int*       counts = (unsigned int*)(ws + 256);
    float*              esq    = (float*)(ws + 8192);
    uint4*              cbhi   = (uint4*)(ws + 16384);
    uint4*              cblo   = (uint4*)(ws + 16384 + 131072);

    vq_prep<<<4, 256, 0, stream>>>(cb, esq, cbhi, cblo, counts, loss, done);
    vq_main<<<NBLK, THREADS, 0, stream>>>(x, cb, esq, cbhi, cblo,
                                          out + 1, loss, counts, done, out);
}

// Round 6
// 202.313 us; speedup vs baseline: 1.2980x; 1.2980x over previous
//
#include <hip/hip_runtime.h>
#include <math.h>

#define N_ROWS 131072
#define DIM 64
#define K_CODES 1024
#define CHUNK 256
#define BLK_ROWS 256
#define THREADS 256
#define NBLK (N_ROWS / BLK_ROWS)   // 512

typedef __attribute__((ext_vector_type(8))) short bf16x8;
typedef __attribute__((ext_vector_type(4))) float f32x4;

__device__ inline unsigned short bf16_rn(float f) {
    unsigned int u = __builtin_bit_cast(unsigned int, f);
    u += 0x7fffu + ((u >> 16) & 1u);   // round-to-nearest-even
    return (unsigned short)(u >> 16);
}
__device__ inline float bf16_to_f(unsigned short h) {
    unsigned int u = ((unsigned int)h) << 16;
    return __builtin_bit_cast(float, u);
}

// ws layout:
//   [0,8)    double loss_sum        [128,132) u32 done
//   [256,4352) u32 counts[1024]     [8192,12288) f32 esq[1024]
//   [16384,+128K) bf16 cbhi = bf16(-2c)   [147456,+128K) bf16 cblo = bf16(-2c - hi)

__global__ void vq_prep(const float* __restrict__ cb, float* __restrict__ esq,
                        uint4* __restrict__ cbhi, uint4* __restrict__ cblo,
                        unsigned int* __restrict__ counts,
                        unsigned long long* __restrict__ loss,
                        unsigned int* __restrict__ done) {
    const int k = blockIdx.x * blockDim.x + threadIdx.x;   // one code per thread
    if (k >= K_CODES) return;
    counts[k] = 0u;
    if (k == 0) { *loss = 0ull; *done = 0u; }
    const float4* c = (const float4*)(cb + (size_t)k * DIM);
    float s = 0.f;
#pragma unroll
    for (int i = 0; i < 8; ++i) {
        float4 a = c[2 * i], b = c[2 * i + 1];
        float f[8] = {a.x, a.y, a.z, a.w, b.x, b.y, b.z, b.w};
        unsigned int hw[4], lw[4];
#pragma unroll
        for (int p = 0; p < 4; ++p) {
            float f0 = f[2 * p], f1 = f[2 * p + 1];
            s = fmaf(f0, f0, s);
            s = fmaf(f1, f1, s);
            float m0 = -2.f * f0, m1 = -2.f * f1;      // exact scaling
            unsigned short h0 = bf16_rn(m0), h1 = bf16_rn(m1);
            unsigned short l0 = bf16_rn(m0 - bf16_to_f(h0));
            unsigned short l1 = bf16_rn(m1 - bf16_to_f(h1));
            hw[p] = (unsigned int)h0 | ((unsigned int)h1 << 16);
            lw[p] = (unsigned int)l0 | ((unsigned int)l1 << 16);
        }
        cbhi[(size_t)k * 8 + i] = make_uint4(hw[0], hw[1], hw[2], hw[3]);
        cblo[(size_t)k * 8 + i] = make_uint4(lw[0], lw[1], lw[2], lw[3]);
    }
    esq[k] = s;
}

__global__ __launch_bounds__(THREADS, 2) void vq_main(
    const float* __restrict__ x, const float* __restrict__ cb,
    const float* __restrict__ esq_g,
    const uint4* __restrict__ cbhi, const uint4* __restrict__ cblo,
    float* __restrict__ outq,
    unsigned long long* __restrict__ loss_sum,
    unsigned int* __restrict__ counts,
    unsigned int* __restrict__ done,
    float* __restrict__ out)
{
    __shared__ __align__(16) char s_ab[CHUNK * 256];   // hi [0,32K) + lo [32K,64K)
    __shared__ __align__(16) float s_esq[K_CODES];     // 4 KB
    __shared__ float s_red[THREADS];
    __shared__ int s_last;

    const int t  = threadIdx.x;
    const int w  = t >> 6;        // wave 0..3
    const int l  = t & 63;        // lane
    const int g  = l >> 4;        // k-group 0..3
    const int li = l & 15;

    const int R0 = blockIdx.x * BLK_ROWS;

    // ---- x rows -> split-bf16 B fragments, registers all kernel ----
    bf16x8 xh[4][2], xl[4][2];
#pragma unroll
    for (int rg = 0; rg < 4; ++rg) {
        const int row = R0 + w * 64 + rg * 16 + li;
        const float* xp = x + (size_t)row * DIM;
#pragma unroll
        for (int h = 0; h < 2; ++h) {
            const float4 p0 = *(const float4*)(xp + h * 32 + g * 8);
            const float4 p1 = *(const float4*)(xp + h * 32 + g * 8 + 4);
            float f[8] = {p0.x, p0.y, p0.z, p0.w, p1.x, p1.y, p1.z, p1.w};
            bf16x8 hv, lv;
#pragma unroll
            for (int j = 0; j < 8; ++j) {
                unsigned short hb = bf16_rn(f[j]);
                unsigned short lb = bf16_rn(f[j] - bf16_to_f(hb));
                hv[j] = (short)hb;
                lv[j] = (short)lb;
            }
            xh[rg][h] = hv;
            xl[rg][h] = lv;
        }
    }

    ((float4*)s_esq)[t] = ((const float4*)esq_g)[t];   // covered by chunk-0 barrier

    float best[4];
    int   bidx[4];
#pragma unroll
    for (int rg = 0; rg < 4; ++rg) { best[rg] = 3.4e38f; bidx[rg] = 0; }

    // per-lane swizzle is tb-invariant: c = tb*16+li -> c&7 == li&7
    const int sw = li & 7;
    const int aoff0 = li * 128 + ((g ^ sw) << 4);        // k-slot g   (k 0..31)
    const int aoff1 = li * 128 + (((4 + g) ^ sw) << 4);  // k-slot 4+g (k 32..63)

    for (int chunk = 0; chunk < K_CODES / CHUNK; ++chunk) {
        if (chunk) __syncthreads();
#pragma unroll
        for (int i = 0; i < 8; ++i) {
            const int n = i * THREADS + t;
            const int c = n >> 3, s = n & 7;
            const int dst = c * 128 + ((s ^ (c & 7)) << 4);
            *(uint4*)(s_ab + dst)         = cbhi[(size_t)(chunk * CHUNK + c) * 8 + s];
            *(uint4*)(s_ab + 32768 + dst) = cblo[(size_t)(chunk * CHUNK + c) * 8 + s];
        }
        __syncthreads();

#pragma unroll 1
        for (int tb = 0; tb < CHUNK / 16; ++tb) {
            // single frag set (round-2 register geometry)
            const int a0 = aoff0 + tb * 2048;
            const int a1 = aoff1 + tb * 2048;
            const bf16x8 ah0 = *(const bf16x8*)(s_ab + a0);
            const bf16x8 ah1 = *(const bf16x8*)(s_ab + a1);
            const bf16x8 al0 = *(const bf16x8*)(s_ab + 32768 + a0);
            const bf16x8 al1 = *(const bf16x8*)(s_ab + 32768 + a1);
            const int kb = chunk * CHUNK + tb * 16 + g * 4;
            const float4 e4 = *(const float4*)(s_esq + kb);

            // term-outer / rg-inner: 4 independent MFMA chains, acc init = esq
            f32x4 acc[4];
#pragma unroll
            for (int rg = 0; rg < 4; ++rg)
                acc[rg] = (f32x4){e4.x, e4.y, e4.z, e4.w};
#pragma unroll
            for (int rg = 0; rg < 4; ++rg)
                acc[rg] = __builtin_amdgcn_mfma_f32_16x16x32_bf16(ah0, xh[rg][0], acc[rg], 0, 0, 0);
#pragma unroll
            for (int rg = 0; rg < 4; ++rg)
                acc[rg] = __builtin_amdgcn_mfma_f32_16x16x32_bf16(ah1, xh[rg][1], acc[rg], 0, 0, 0);
#pragma unroll
            for (int rg = 0; rg < 4; ++rg)
                acc[rg] = __builtin_amdgcn_mfma_f32_16x16x32_bf16(ah0, xl[rg][0], acc[rg], 0, 0, 0);
#pragma unroll
            for (int rg = 0; rg < 4; ++rg)
                acc[rg] = __builtin_amdgcn_mfma_f32_16x16x32_bf16(ah1, xl[rg][1], acc[rg], 0, 0, 0);
#pragma unroll
            for (int rg = 0; rg < 4; ++rg)
                acc[rg] = __builtin_amdgcn_mfma_f32_16x16x32_bf16(al0, xh[rg][0], acc[rg], 0, 0, 0);
#pragma unroll
            for (int rg = 0; rg < 4; ++rg)
                acc[rg] = __builtin_amdgcn_mfma_f32_16x16x32_bf16(al1, xh[rg][1], acc[rg], 0, 0, 0);

            // compare (acc IS dist'); ascending code + strict '<' = first-min
#pragma unroll
            for (int rg = 0; rg < 4; ++rg) {
#pragma unroll
                for (int j = 0; j < 4; ++j) {
                    float tv = acc[rg][j];
                    if (tv < best[rg]) { best[rg] = tv; bidx[rg] = kb + j; }
                }
            }
        }
    }

    // ---- merge argmin across the 4 k-groups ----
#pragma unroll
    for (int rg = 0; rg < 4; ++rg) {
#pragma unroll
        for (int d = 16; d <= 32; d <<= 1) {
            float ob = __shfl_xor(best[rg], d, 64);
            int   oi = __shfl_xor(bidx[rg], d, 64);
            if (ob < best[rg] || (ob == best[rg] && oi < bidx[rg])) {
                best[rg] = ob;
                bidx[rg] = oi;
            }
        }
    }

    // ---- epilogue: gather code, write quantized, loss partial, histogram ----
    float ls = 0.f;
#pragma unroll
    for (int rg = 0; rg < 4; ++rg) {
        const int row = R0 + w * 64 + rg * 16 + li;
        const int idx = bidx[rg];
        if (g == 0) atomicAdd(&counts[idx], 1u);
        const float4* qp = (const float4*)(cb + (size_t)idx * DIM);
        float* op = outq + (size_t)row * DIM;
#pragma unroll
        for (int h = 0; h < 2; ++h) {
            float4 q0 = qp[h * 8 + g * 2];
            float4 q1 = qp[h * 8 + g * 2 + 1];
            *(float4*)(op + h * 32 + g * 8)     = q0;
            *(float4*)(op + h * 32 + g * 8 + 4) = q1;
            float qq[8] = {q0.x, q0.y, q0.z, q0.w, q1.x, q1.y, q1.z, q1.w};
#pragma unroll
            for (int j = 0; j < 8; ++j) {
                float xv = bf16_to_f((unsigned short)xh[rg][h][j])
                         + bf16_to_f((unsigned short)xl[rg][h][j]);
                float e = qq[j] - xv;
                ls = fmaf(e, e, ls);
            }
        }
    }

    s_red[t] = ls;
    __syncthreads();
#pragma unroll
    for (int s = THREADS / 2; s > 0; s >>= 1) {
        if (t < s) s_red[t] += s_red[t + s];
        __syncthreads();
    }
    if (t == 0) atomicAdd((double*)loss_sum, (double)s_red[0]);

    // ---- last block finalizes loss + perplexity ----
    if (t == 0) {
        __threadfence();
        unsigned int prev = __hip_atomic_fetch_add(done, 1u, __ATOMIC_ACQ_REL,
                                                   __HIP_MEMORY_SCOPE_AGENT);
        s_last = (prev == (unsigned int)(NBLK - 1));
    }
    __syncthreads();
    if (s_last) {
        float part = 0.f;
#pragma unroll
        for (int j = 0; j < 4; ++j) {
            unsigned int c = __hip_atomic_load(&counts[t + j * 256], __ATOMIC_RELAXED,
                                               __HIP_MEMORY_SCOPE_AGENT);
            float pr = (float)c * (1.0f / (float)N_ROWS);
            part += pr * logf(pr + 1e-10f);
        }
        s_red[t] = part;
        __syncthreads();
#pragma unroll
        for (int s = THREADS / 2; s > 0; s >>= 1) {
            if (t < s) s_red[t] += s_red[t + s];
            __syncthreads();
        }
        if (t == 0) {
            unsigned long long lb = __hip_atomic_load(loss_sum, __ATOMIC_RELAXED,
                                                      __HIP_MEMORY_SCOPE_AGENT);
            double ls_d = __builtin_bit_cast(double, lb);
            out[0] = (float)(1.25 * ls_d / (double)((size_t)N_ROWS * DIM));
            out[1 + (size_t)N_ROWS * DIM] = expf(-s_red[0]);
        }
    }
}

extern "C" void kernel_launch(void* const* d_in, const int* in_sizes, int n_in,
                              void* d_out, int out_size, void* d_ws, size_t ws_size,
                              hipStream_t stream) {
    const float* x  = (const float*)d_in[0];   // [131072, 64] f32
    const float* cb = (const float*)d_in[1];   // [1024, 64] f32
    float* out = (float*)d_out;                // [1 + N*D + 1] f32
    char* ws = (char*)d_ws;

    unsigned long long* loss   = (unsigned long long*)ws;
    unsigned int*       done   = (unsigned int*)(ws + 128);
    unsigned int*       counts = (unsigned int*)(ws + 256);
    float*              esq    = (float*)(ws + 8192);
    uint4*              cbhi   = (uint4*)(ws + 16384);
    uint4*              cblo   = (uint4*)(ws + 16384 + 131072);

    vq_prep<<<4, 256, 0, stream>>>(cb, esq, cbhi, cblo, counts, loss, done);
    vq_main<<<NBLK, THREADS, 0, stream>>>(x, cb, esq, cbhi, cblo,
                                          out + 1, loss, counts, done, out);
}